// Round 1
// 160.679 us; speedup vs baseline: 1.1273x; 1.1273x over previous
//
#include <hip/hip_runtime.h>
#include <hip/hip_bf16.h>
#include <cstddef>

#define DIMC   768
#define HEADS  12
#define BATCH  4
#define SEQ    2048
#define MROWS  (BATCH * SEQ)      // 8192
#define NCAT   1920               // Wtcat rows: 768 (Wa) + 384 (Wb) + 768 (Wv)
#define NAB    1152               // gemm1 output width ([Wa|Wb] only)

typedef unsigned short u16;
typedef __attribute__((ext_vector_type(8))) short short8;   // 8 bf16 = 4 VGPRs
typedef __attribute__((ext_vector_type(4))) float floatx4;  // MFMA C/D

__device__ inline u16 f2bf(float f) {
    union { float f; unsigned u; } v; v.f = f;
    unsigned u = v.u + 0x7FFF + ((v.u >> 16) & 1);   // RNE
    return (u16)(u >> 16);
}
__device__ inline float bf2f(u16 h) {
    union { unsigned u; float f; } v; v.u = ((unsigned)h) << 16;
    return v.f;
}

// async 16B/lane global->LDS; lane i lands at lptr + i*16 (wave-uniform base)
__device__ inline void async_load16(const void* g, void* l) {
    __builtin_amdgcn_global_load_lds(
        (const __attribute__((address_space(1))) void*)g,
        (__attribute__((address_space(3))) void*)l, 16, 0, 0);
}

// ---------------------------------------------------------------------------
// Fused prep (unchanged):
//  [0,3072)      x fp32 -> xb bf16 (8 elem/thread)
//  [3072,3432)   Wtcat 64x64 tile-transpose from [Wa|Wb|Wv]
//  [3432,3576)   Wpt from Wp
//  [3576,3832)   xs-pool: xs[p][c] = sum_{j<32} x[(p*32+j)*768 + c] (bf16)
// ---------------------------------------------------------------------------
__global__ __launch_bounds__(256)
void prep_kernel(const float* __restrict__ x,
                 const float* __restrict__ Wa, const float* __restrict__ Wb,
                 const float* __restrict__ Wv, const float* __restrict__ Wp,
                 u16* __restrict__ xb, u16* __restrict__ Wtcat,
                 u16* __restrict__ Wpt, u16* __restrict__ xs)
{
    const int tid = threadIdx.x;
    const int bidg = blockIdx.x;
    if (bidg < 3072) {
        int i = bidg * 256 + tid;
        const float4 f0 = ((const float4*)x)[(size_t)i * 2];
        const float4 f1 = ((const float4*)x)[(size_t)i * 2 + 1];
        u16 tmp[8] = { f2bf(f0.x), f2bf(f0.y), f2bf(f0.z), f2bf(f0.w),
                       f2bf(f1.x), f2bf(f1.y), f2bf(f1.z), f2bf(f1.w) };
        *(uint4*)&xb[(size_t)i * 8] = *(uint4*)tmp;
        return;
    }
    if (bidg >= 3576) {
        // xs-pool: one pooled row per block, 3 coalesced column passes
        const int p = bidg - 3576;                 // [0,256)
#pragma unroll
        for (int k = 0; k < 3; ++k) {
            const int c = k * 256 + tid;
            const float* src = x + (size_t)p * 32 * DIMC + c;
            float s = 0.f;
#pragma unroll
            for (int j = 0; j < 32; ++j) s += src[(size_t)j * DIMC];
            xs[(size_t)p * DIMC + c] = f2bf(s);
        }
        return;
    }
    __shared__ u16 tile[64 * 72];
    int bid = bidg - 3072;
    const float* src; u16* dst; int n0, k0, ld, col0;
    if (bid < 360) {
        int nt = bid / 12, kt = bid % 12;
        n0 = nt * 64; k0 = kt * 64; dst = Wtcat;
        if (n0 < 768)       { src = Wa; ld = 768; col0 = n0; }
        else if (n0 < 1152) { src = Wb; ld = 384; col0 = n0 - 768; }
        else                { src = Wv; ld = 768; col0 = n0 - 1152; }
    } else {
        int b2 = bid - 360;
        int nt = b2 / 12, kt = b2 % 12;
        n0 = nt * 64; k0 = kt * 64; dst = Wpt; src = Wp; ld = 768; col0 = n0;
    }
#pragma unroll
    for (int p = 0; p < 16; ++p) {
        int i = p * 256 + tid;
        int k = i >> 6, n = i & 63;
        tile[n * 72 + k] = f2bf(src[(size_t)(k0 + k) * ld + col0 + n]);
    }
    __syncthreads();
    int n = tid >> 2, kc = (tid & 3) * 16;
    uint4 o0 = *(uint4*)&tile[n * 72 + kc];
    uint4 o1 = *(uint4*)&tile[n * 72 + kc + 8];
    *(uint4*)&dst[(size_t)(n0 + n) * DIMC + k0 + kc] = o0;
    *(uint4*)&dst[(size_t)(n0 + n) * DIMC + k0 + kc + 8] = o1;
}

// ---------------------------------------------------------------------------
// bf16 MFMA GEMM — unchanged (validated). C[M,N] = A[M,K] @ Bt[N,K]^T (+bias).
// ---------------------------------------------------------------------------
template<bool WRITE_BF16>
__global__ __launch_bounds__(256)
void gemm_bf16_kernel(const u16* __restrict__ A, const u16* __restrict__ Bt,
                      const float* __restrict__ bias, void* __restrict__ Cout,
                      int K, int ldC)
{
    __shared__ u16 As[2][4096];
    __shared__ u16 Bs[2][4096];

    const int tid  = threadIdx.x;
    const int lane = tid & 63, wave = tid >> 6;
    const int quad = lane >> 4, l16 = lane & 15;
    const int wm = (wave & 1) * 64, wn = (wave >> 1) * 64;
    const int m0 = blockIdx.x * 128, n0 = blockIdx.y * 128;

    const int lrow = lane >> 2, lchunk = lane & 3;
    const u16* gA = A  + (size_t)(m0 + wave * 32 + lrow) * K + lchunk * 8;
    const u16* gB = Bt + (size_t)(n0 + wave * 32 + lrow) * K + lchunk * 8;
    const int NT = K / 32;   // 24

#define STAGE(buf, kt_) do {                                                  \
        const int _k0 = (kt_) * 32;                                           \
        async_load16(gA + _k0,          &As[buf][wave * 1024]);               \
        async_load16(gA + _k0 + 16 * K, &As[buf][wave * 1024 + 512]);         \
        async_load16(gB + _k0,          &Bs[buf][wave * 1024]);               \
        async_load16(gB + _k0 + 16 * K, &Bs[buf][wave * 1024 + 512]);         \
    } while (0)

#define COMPUTE(buf) do {                                                     \
        short8 af[4], bf[4];                                                  \
        _Pragma("unroll")                                                     \
        for (int t = 0; t < 4; ++t) {                                         \
            af[t] = *(short8*)&As[buf][(wm + t * 16 + l16) * 32 + quad * 8];  \
            bf[t] = *(short8*)&Bs[buf][(wn + t * 16 + l16) * 32 + quad * 8];  \
        }                                                                     \
        _Pragma("unroll")                                                     \
        for (int mt = 0; mt < 4; ++mt)                                        \
            _Pragma("unroll")                                                 \
            for (int nt = 0; nt < 4; ++nt)                                    \
                acc[mt][nt] = __builtin_amdgcn_mfma_f32_16x16x32_bf16(        \
                    af[mt], bf[nt], acc[mt][nt], 0, 0, 0);                    \
    } while (0)

    floatx4 acc[4][4] = {};
    STAGE(0, 0);
    STAGE(1, 1);
#pragma unroll 2
    for (int kt = 0; kt < NT; ++kt) {
        const int buf = kt & 1;
        __asm__ volatile("s_waitcnt vmcnt(4)" ::: "memory");  // retire older 4
        __asm__ volatile("s_barrier" ::: "memory");
        COMPUTE(buf);
        __asm__ volatile("s_barrier" ::: "memory");
        STAGE(buf, (kt + 2) % NT);
    }
#undef STAGE
#undef COMPUTE

#pragma unroll
    for (int mt = 0; mt < 4; ++mt)
#pragma unroll
        for (int nt = 0; nt < 4; ++nt) {
            const int gc = n0 + wn + nt * 16 + l16;
            const float bv = bias ? bias[gc] : 0.f;
#pragma unroll
            for (int r = 0; r < 4; ++r) {
                const int gr = m0 + wm + mt * 16 + quad * 4 + r;
                const float v = acc[mt][nt][r] + bv;
                if (WRITE_BF16) ((u16*)Cout)[(size_t)gr * ldC + gc] = f2bf(v);
                else            ((float*)Cout)[(size_t)gr * ldC + gc] = v;
            }
        }
}

// ---------------------------------------------------------------------------
// Vs kernel — NOW TRANSPOSED OUTPUT, bf16.
// VsT[bh][d][t] = Wvt[h*64+d] . xs[b*64+t]  (A=Wvt rows, Bt=xs rows — same
// validated operand arrangement as the GEMM, with A/B roles swapped so the
// MFMA emits the transpose directly; coalesced bf16 C-write, no LDS).
// ---------------------------------------------------------------------------
__global__ __launch_bounds__(256)
void vs_kernel(const u16* __restrict__ xs, const u16* __restrict__ Wvt,
               u16* __restrict__ VsT)
{
    const int tid = threadIdx.x;
    const int lane = tid & 63, wave = tid >> 6;
    const int quad = lane >> 4, l16 = lane & 15;
    const int bh = blockIdx.x;
    const int b = bh / HEADS, h = bh % HEADS;
    const int K = DIMC;

    const u16* gA = Wvt + (size_t)(h * 64 + wave * 16 + l16) * K + quad * 8;
    const u16* gB = xs  + (size_t)(b * 64 + l16) * K + quad * 8;

    floatx4 acc[4] = {};
    for (int it = 0; it < 24; ++it) {
        short8 af = *(const short8*)(gA + it * 32);
        short8 bf[4];
#pragma unroll
        for (int nt = 0; nt < 4; ++nt)
            bf[nt] = *(const short8*)(gB + (size_t)nt * 16 * K + it * 32);
#pragma unroll
        for (int nt = 0; nt < 4; ++nt)
            acc[nt] = __builtin_amdgcn_mfma_f32_16x16x32_bf16(
                af, bf[nt], acc[nt], 0, 0, 0);
    }
#pragma unroll
    for (int nt = 0; nt < 4; ++nt)
#pragma unroll
        for (int r = 0; r < 4; ++r) {
            const int d = wave * 16 + quad * 4 + r;   // output row (head dim)
            const int t = nt * 16 + l16;              // output col (pooled key)
            VsT[(size_t)bh * 4096 + d * 64 + t] = f2bf(acc[nt][r]);
        }
}

// ---------------------------------------------------------------------------
// Attention — restructured:
//  * V fragments loaded directly from global VsT (bf16, [d][t]) — no LDS
//    staging, no 32-way-conflicted transpose, no __syncthreads at all.
//  * Softmax: no max subtraction (|s| <~ 8, exp is fp32-safe), no shuffles.
//    Unnormalized e -> per-wave LDS (stride 72, conflict-free), row sums via
//    one extra MFMA against an all-ones B fragment (sums land in exactly the
//    C-rows each lane needs); normalize accumulator after PV.
// ---------------------------------------------------------------------------
__global__ __launch_bounds__(256)
void attn_kernel(const u16* __restrict__ Yab, const u16* __restrict__ VsT,
                 u16* __restrict__ Hb)
{
    __shared__ u16 wlds[4][16 * 72];    // per-wave P [r][k], padded stride 72
    const int bh = blockIdx.x;
    const int h = bh % HEADS, b = bh / HEADS;
    const int tid = threadIdx.x;
    const int lane = tid & 63, wave = tid >> 6;
    const int quad = lane >> 4, l16 = lane & 15;

    // V fragments straight from global (8KB/bh, L2-hot, reused by 32 blocks)
    const u16* vbase = VsT + (size_t)bh * 4096;
    short8 bfrag[4][2];
#pragma unroll
    for (int nt = 0; nt < 4; ++nt)
#pragma unroll
        for (int kk = 0; kk < 2; ++kk)
            bfrag[nt][kk] = *(const short8*)
                &vbase[(nt * 16 + l16) * 64 + kk * 32 + quad * 8];

    const int i0 = blockIdx.y * 64 + wave * 16;
    const u16* yrow = Yab + (size_t)(b * SEQ + i0) * NAB;
    u16* wp = &wlds[wave][0];

#pragma unroll
    for (int r = 0; r < 16; ++r) {
        float aval = bf2f(yrow[(size_t)r * NAB + h * 64 + lane]);
        float bval = bf2f(yrow[(size_t)r * NAB + 768 + h * 32 + (lane >> 1)]);
        wp[r * 72 + lane] = f2bf(__expf(aval * bval));   // unnormalized
    }

    short8 af0 = *(short8*)&wp[l16 * 72 + quad * 8];
    short8 af1 = *(short8*)&wp[l16 * 72 + 32 + quad * 8];

    short8 ones;
#pragma unroll
    for (int j = 0; j < 8; ++j) ones[j] = (short)0x3F80;   // bf16 1.0

    floatx4 acc[4] = {};
    floatx4 sacc = {};
#pragma unroll
    for (int nt = 0; nt < 4; ++nt) {
        acc[nt] = __builtin_amdgcn_mfma_f32_16x16x32_bf16(af0, bfrag[nt][0], acc[nt], 0, 0, 0);
        acc[nt] = __builtin_amdgcn_mfma_f32_16x16x32_bf16(af1, bfrag[nt][1], acc[nt], 0, 0, 0);
    }
    // row sums: C[i][j] = sum_k P[i][k] * 1 for every j; lane's reg r is row
    // quad*4+r — exactly the rows its acc[] holds.
    sacc = __builtin_amdgcn_mfma_f32_16x16x32_bf16(af0, ones, sacc, 0, 0, 0);
    sacc = __builtin_amdgcn_mfma_f32_16x16x32_bf16(af1, ones, sacc, 0, 0, 0);

    float inv[4];
#pragma unroll
    for (int r = 0; r < 4; ++r) inv[r] = 1.0f / (32.0f * sacc[r]);

#pragma unroll
    for (int nt = 0; nt < 4; ++nt)
#pragma unroll
        for (int rr = 0; rr < 4; ++rr) {
            const size_t row = (size_t)(b * SEQ + i0 + quad * 4 + rr);
            Hb[row * DIMC + h * 64 + nt * 16 + l16] = f2bf(acc[nt][rr] * inv[rr]);
        }
}

// ---------------------------------------------------------------------------
extern "C" void kernel_launch(void* const* d_in, const int* in_sizes, int n_in,
                              void* d_out, int out_size, void* d_ws, size_t ws_size,
                              hipStream_t stream)
{
    const float* x  = (const float*)d_in[0];
    const float* Wa = (const float*)d_in[1];
    const float* Wb = (const float*)d_in[2];
    const float* Wv = (const float*)d_in[3];
    const float* Wp = (const float*)d_in[4];
    const float* bp = (const float*)d_in[5];
    float* out = (float*)d_out;

    char* ws = (char*)d_ws;
    u16*   xb    = (u16*)ws;   ws += (size_t)MROWS * DIMC * 2;   // 12.6 MB
    u16*   Wtcat = (u16*)ws;   ws += (size_t)NCAT * DIMC * 2;    // 2.9 MB
    u16*   Wpt   = (u16*)ws;   ws += (size_t)DIMC * DIMC * 2;    // 1.2 MB
    u16*   xs    = (u16*)ws;   ws += (size_t)256 * DIMC * 2;     // 0.4 MB
    u16*   Yab   = (u16*)ws;   ws += (size_t)MROWS * NAB * 2;    // 18.9 MB
    u16*   VsT   = (u16*)ws;   ws += (size_t)48 * 4096 * 2;      // 0.4 MB
    u16*   Hb    = (u16*)ws;                                     // 12.6 MB

    dim3 blk(256);

    prep_kernel<<<dim3(3832), blk, 0, stream>>>(x, Wa, Wb, Wv, Wp,
                                                xb, Wtcat, Wpt, xs);

    vs_kernel<<<dim3(48), blk, 0, stream>>>(xs, Wtcat + (size_t)NAB * DIMC, VsT);

    gemm_bf16_kernel<true><<<dim3(MROWS / 128, NAB / 128), blk, 0, stream>>>(
        xb, Wtcat, nullptr, Yab, DIMC, NAB);

    attn_kernel<<<dim3(BATCH * HEADS, SEQ / 64), blk, 0, stream>>>(Yab, VsT, Hb);

    gemm_bf16_kernel<false><<<dim3(MROWS / 128, DIMC / 128), blk, 0, stream>>>(
        Hb, Wpt, bp, out, DIMC, DIMC);
}

// Round 3
// 160.147 us; speedup vs baseline: 1.1310x; 1.0033x over previous
//
#include <hip/hip_runtime.h>
#include <hip/hip_bf16.h>
#include <cstddef>

#define DIMC   768
#define HEADS  12
#define BATCH  4
#define SEQ    2048
#define MROWS  (BATCH * SEQ)      // 8192
#define NCAT   1920               // Wtcat rows: 1152 (head-major [Wa|Wb]) + 768 (Wv)
#define NAB    1152

typedef unsigned short u16;
typedef __attribute__((ext_vector_type(8))) short short8;   // 8 bf16 = 4 VGPRs
typedef __attribute__((ext_vector_type(4))) float floatx4;  // MFMA C/D

__device__ inline u16 f2bf(float f) {
    union { float f; unsigned u; } v; v.f = f;
    unsigned u = v.u + 0x7FFF + ((v.u >> 16) & 1);   // RNE
    return (u16)(u >> 16);
}
__device__ inline float bf2f(u16 h) {
    union { unsigned u; float f; } v; v.u = ((unsigned)h) << 16;
    return v.f;
}

// async 16B/lane global->LDS; lane i lands at lptr + i*16 (wave-uniform base)
__device__ inline void async_load16(const void* g, void* l) {
    __builtin_amdgcn_global_load_lds(
        (const __attribute__((address_space(1))) void*)g,
        (__attribute__((address_space(3))) void*)l, 16, 0, 0);
}

// ---------------------------------------------------------------------------
// Fused prep:
//  [0,3072)      x fp32 -> xb bf16 (8 elem/thread)
//  [3072,3432)   Wtcat 64x64 tile-transpose from [Wa|Wb|Wv]
//                ab rows HEAD-MAJOR: head h rows [h*96,h*96+96) =
//                64 Wa cols (h*64..) then 32 Wb cols (h*32..)
//  [3432,3576)   Wpt from Wp
//  [3576,3832)   xs-pool: xs[p][c] = sum_{j<32} x[(p*32+j)*768 + c] (bf16)
// ---------------------------------------------------------------------------
__global__ __launch_bounds__(256)
void prep_kernel(const float* __restrict__ x,
                 const float* __restrict__ Wa, const float* __restrict__ Wb,
                 const float* __restrict__ Wv, const float* __restrict__ Wp,
                 u16* __restrict__ xb, u16* __restrict__ Wtcat,
                 u16* __restrict__ Wpt, u16* __restrict__ xs)
{
    const int tid = threadIdx.x;
    const int bidg = blockIdx.x;
    if (bidg < 3072) {
        int i = bidg * 256 + tid;
        const float4 f0 = ((const float4*)x)[(size_t)i * 2];
        const float4 f1 = ((const float4*)x)[(size_t)i * 2 + 1];
        u16 tmp[8] = { f2bf(f0.x), f2bf(f0.y), f2bf(f0.z), f2bf(f0.w),
                       f2bf(f1.x), f2bf(f1.y), f2bf(f1.z), f2bf(f1.w) };
        *(uint4*)&xb[(size_t)i * 8] = *(uint4*)tmp;
        return;
    }
    if (bidg >= 3576) {
        const int p = bidg - 3576;                 // [0,256)
#pragma unroll
        for (int k = 0; k < 3; ++k) {
            const int c = k * 256 + tid;
            const float* src = x + (size_t)p * 32 * DIMC + c;
            float s = 0.f;
#pragma unroll
            for (int j = 0; j < 32; ++j) s += src[(size_t)j * DIMC];
            xs[(size_t)p * DIMC + c] = f2bf(s);
        }
        return;
    }
    __shared__ u16 tile[64 * 72];
    int bid = bidg - 3072;
    const float* src; u16* dst; int n0, k0, ld, col0;
    bool remap = false;
    if (bid < 360) {
        int nt = bid / 12, kt = bid % 12;
        n0 = nt * 64; k0 = kt * 64; dst = Wtcat;
        if (n0 < 768)       { src = Wa; ld = 768; col0 = n0; remap = true; }
        else if (n0 < 1152) { src = Wb; ld = 384; col0 = n0 - 768; remap = true; }
        else                { src = Wv; ld = 768; col0 = n0 - 1152; }
    } else {
        int b2 = bid - 360;
        int nt = b2 / 12, kt = b2 % 12;
        n0 = nt * 64; k0 = kt * 64; dst = Wpt; src = Wp; ld = 768; col0 = n0;
    }
#pragma unroll
    for (int p = 0; p < 16; ++p) {
        int i = p * 256 + tid;
        int k = i >> 6, n = i & 63;
        tile[n * 72 + k] = f2bf(src[(size_t)(k0 + k) * ld + col0 + n]);
    }
    __syncthreads();
    int n = tid >> 2, kc = (tid & 3) * 16;
    int orow = n0 + n;
    int drow = orow;
    if (remap) {
        if (orow < 768) drow = (orow >> 6) * 96 + (orow & 63);              // Wa
        else { int c = orow - 768; drow = (c >> 5) * 96 + 64 + (c & 31); }  // Wb
    }
    uint4 o0 = *(uint4*)&tile[n * 72 + kc];
    uint4 o1 = *(uint4*)&tile[n * 72 + kc + 8];
    *(uint4*)&dst[(size_t)drow * DIMC + k0 + kc] = o0;
    *(uint4*)&dst[(size_t)drow * DIMC + k0 + kc + 8] = o1;
}

// ---------------------------------------------------------------------------
// bf16 MFMA GEMM — validated; used for gemm2 only.
// ---------------------------------------------------------------------------
template<bool WRITE_BF16>
__global__ __launch_bounds__(256)
void gemm_bf16_kernel(const u16* __restrict__ A, const u16* __restrict__ Bt,
                      const float* __restrict__ bias, void* __restrict__ Cout,
                      int K, int ldC)
{
    __shared__ u16 As[2][4096];
    __shared__ u16 Bs[2][4096];

    const int tid  = threadIdx.x;
    const int lane = tid & 63, wave = tid >> 6;
    const int quad = lane >> 4, l16 = lane & 15;
    const int wm = (wave & 1) * 64, wn = (wave >> 1) * 64;
    const int m0 = blockIdx.x * 128, n0 = blockIdx.y * 128;

    const int lrow = lane >> 2, lchunk = lane & 3;
    const u16* gA = A  + (size_t)(m0 + wave * 32 + lrow) * K + lchunk * 8;
    const u16* gB = Bt + (size_t)(n0 + wave * 32 + lrow) * K + lchunk * 8;
    const int NT = K / 32;   // 24

#define STAGE(buf, kt_) do {                                                  \
        const int _k0 = (kt_) * 32;                                           \
        async_load16(gA + _k0,          &As[buf][wave * 1024]);               \
        async_load16(gA + _k0 + 16 * K, &As[buf][wave * 1024 + 512]);         \
        async_load16(gB + _k0,          &Bs[buf][wave * 1024]);               \
        async_load16(gB + _k0 + 16 * K, &Bs[buf][wave * 1024 + 512]);         \
    } while (0)

#define COMPUTE(buf) do {                                                     \
        short8 af[4], bf[4];                                                  \
        _Pragma("unroll")                                                     \
        for (int t = 0; t < 4; ++t) {                                         \
            af[t] = *(short8*)&As[buf][(wm + t * 16 + l16) * 32 + quad * 8];  \
            bf[t] = *(short8*)&Bs[buf][(wn + t * 16 + l16) * 32 + quad * 8];  \
        }                                                                     \
        _Pragma("unroll")                                                     \
        for (int mt = 0; mt < 4; ++mt)                                        \
            _Pragma("unroll")                                                 \
            for (int nt = 0; nt < 4; ++nt)                                    \
                acc[mt][nt] = __builtin_amdgcn_mfma_f32_16x16x32_bf16(        \
                    af[mt], bf[nt], acc[mt][nt], 0, 0, 0);                    \
    } while (0)

    floatx4 acc[4][4] = {};
    STAGE(0, 0);
    STAGE(1, 1);
#pragma unroll 2
    for (int kt = 0; kt < NT; ++kt) {
        const int buf = kt & 1;
        __asm__ volatile("s_waitcnt vmcnt(4)" ::: "memory");
        __asm__ volatile("s_barrier" ::: "memory");
        COMPUTE(buf);
        __asm__ volatile("s_barrier" ::: "memory");
        STAGE(buf, (kt + 2) % NT);
    }
#undef STAGE
#undef COMPUTE

#pragma unroll
    for (int mt = 0; mt < 4; ++mt)
#pragma unroll
        for (int nt = 0; nt < 4; ++nt) {
            const int gc = n0 + wn + nt * 16 + l16;
            const float bv = bias ? bias[gc] : 0.f;
#pragma unroll
            for (int r = 0; r < 4; ++r) {
                const int gr = m0 + wm + mt * 16 + quad * 4 + r;
                const float v = acc[mt][nt][r] + bv;
                if (WRITE_BF16) ((u16*)Cout)[(size_t)gr * ldC + gc] = f2bf(v);
                else            ((float*)Cout)[(size_t)gr * ldC + gc] = v;
            }
        }
}

// ---------------------------------------------------------------------------
// Vs kernel — unchanged (validated). VsT[bh][d][t] bf16.
// ---------------------------------------------------------------------------
__global__ __launch_bounds__(256)
void vs_kernel(const u16* __restrict__ xs, const u16* __restrict__ Wvt,
               u16* __restrict__ VsT)
{
    const int tid = threadIdx.x;
    const int lane = tid & 63, wave = tid >> 6;
    const int quad = lane >> 4, l16 = lane & 15;
    const int bh = blockIdx.x;
    const int b = bh / HEADS, h = bh % HEADS;
    const int K = DIMC;

    const u16* gA = Wvt + (size_t)(h * 64 + wave * 16 + l16) * K + quad * 8;
    const u16* gB = xs  + (size_t)(b * 64 + l16) * K + quad * 8;

    floatx4 acc[4] = {};
    for (int it = 0; it < 24; ++it) {
        short8 af = *(const short8*)(gA + it * 32);
        short8 bf[4];
#pragma unroll
        for (int nt = 0; nt < 4; ++nt)
            bf[nt] = *(const short8*)(gB + (size_t)nt * 16 * K + it * 32);
#pragma unroll
        for (int nt = 0; nt < 4; ++nt)
            acc[nt] = __builtin_amdgcn_mfma_f32_16x16x32_bf16(
                af, bf[nt], acc[nt], 0, 0, 0);
    }
#pragma unroll
    for (int nt = 0; nt < 4; ++nt)
#pragma unroll
        for (int r = 0; r < 4; ++r) {
            const int d = wave * 16 + quad * 4 + r;
            const int t = nt * 16 + l16;
            VsT[(size_t)bh * 4096 + d * 64 + t] = f2bf(acc[nt][r]);
        }
}

// ---------------------------------------------------------------------------
// FUSED gemm1 + attention. Tile 128 rows x 192 cols (= 2 heads).
// Wave w owns rows wm=(w&1)*64, head (w>>1): 64x96 sub-tile = full head.
// K-loop: no wrap-staging (epilogue overlays LDS); tail has
// vmcnt + s_barrier before EVERY compute (cross-wave staging completion).
// ---------------------------------------------------------------------------
__global__ __launch_bounds__(256)
void gemm1_attn_kernel(const u16* __restrict__ xb, const u16* __restrict__ Wab,
                       const u16* __restrict__ VsT, u16* __restrict__ Hb)
{
    __shared__ u16 smem[20480];   // 40 KB: staging during K-loop, P after

    const int tid  = threadIdx.x;
    const int lane = tid & 63, wave = tid >> 6;
    const int quad = lane >> 4, l16 = lane & 15;
    const int wm = (wave & 1) * 64;          // row half
    const int wn = (wave >> 1) * 96;         // col half = one head
    const int m0 = blockIdx.x * 128, n0 = blockIdx.y * 192;
    const int K = DIMC;
    const int NT = K / 32;                   // 24

    const int lrow = lane >> 2, lchunk = lane & 3;
    const u16* gA = xb  + (size_t)(m0 + wave * 32 + lrow) * K + lchunk * 8;
    const u16* gB = Wab + (size_t)(n0 + wave * 48 + lrow) * K + lchunk * 8;

    // As[buf] = smem + buf*4096 (128x32); Bs[buf] = smem + 8192 + buf*6144 (192x32)
#define STAGE(buf, kt_) do {                                                  \
        const int _k0 = (kt_) * 32;                                           \
        u16* _as = smem + (buf) * 4096 + wave * 1024;                         \
        u16* _bs = smem + 8192 + (buf) * 6144 + wave * 1536;                  \
        async_load16(gA + _k0,          _as);                                 \
        async_load16(gA + _k0 + 16 * K, _as + 512);                           \
        async_load16(gB + _k0,          _bs);                                 \
        async_load16(gB + _k0 + 16 * K, _bs + 512);                           \
        async_load16(gB + _k0 + 32 * K, _bs + 1024);                          \
    } while (0)

#define COMPUTE(buf) do {                                                     \
        const u16* _as = smem + (buf) * 4096;                                 \
        const u16* _bs = smem + 8192 + (buf) * 6144;                          \
        short8 af[4], bfr[6];                                                 \
        _Pragma("unroll")                                                     \
        for (int t = 0; t < 4; ++t)                                           \
            af[t] = *(const short8*)&_as[(wm + t * 16 + l16) * 32 + quad * 8];\
        _Pragma("unroll")                                                     \
        for (int t = 0; t < 6; ++t)                                           \
            bfr[t] = *(const short8*)&_bs[(wn + t * 16 + l16) * 32 + quad * 8];\
        _Pragma("unroll")                                                     \
        for (int mt = 0; mt < 4; ++mt)                                        \
            _Pragma("unroll")                                                 \
            for (int ct = 0; ct < 6; ++ct)                                    \
                acc[mt][ct] = __builtin_amdgcn_mfma_f32_16x16x32_bf16(        \
                    af[mt], bfr[ct], acc[mt][ct], 0, 0, 0);                   \
    } while (0)

    floatx4 acc[4][6] = {};
    STAGE(0, 0);
    STAGE(1, 1);
#pragma unroll 2
    for (int kt = 0; kt < NT - 2; ++kt) {
        const int buf = kt & 1;
        __asm__ volatile("s_waitcnt vmcnt(5)" ::: "memory");
        __asm__ volatile("s_barrier" ::: "memory");
        COMPUTE(buf);
        __asm__ volatile("s_barrier" ::: "memory");
        STAGE(buf, kt + 2);
    }
    __asm__ volatile("s_waitcnt vmcnt(5)" ::: "memory");
    __asm__ volatile("s_barrier" ::: "memory");
    COMPUTE(0);                                  // kt = 22
    __asm__ volatile("s_waitcnt vmcnt(0)" ::: "memory");
    __asm__ volatile("s_barrier" ::: "memory");  // FIX: other waves' loads too
    COMPUTE(1);                                  // kt = 23
    __syncthreads();                             // staging LDS dead -> P overlay
#undef STAGE
#undef COMPUTE

    // ---------------- fused attention epilogue (wave-local) ----------------
    const int b = blockIdx.x >> 4;               // m0 / 2048
    const int h = blockIdx.y * 2 + (wave >> 1);
    const u16* vbase = VsT + ((size_t)b * HEADS + h) * 4096;

    short8 bV[4][2];
#pragma unroll
    for (int nt2 = 0; nt2 < 4; ++nt2)
#pragma unroll
        for (int kk = 0; kk < 2; ++kk)
            bV[nt2][kk] = *(const short8*)
                &vbase[(nt2 * 16 + l16) * 64 + kk * 32 + quad * 8];

    u16* Pw = smem + wave * 4608;                // 64 x 72 bf16, per wave
    const int srcl0 = quad * 16 + (l16 >> 1);    // b-col p>>1, frag-local
    const int srcl1 = srcl0 + 8;

    short8 ones;
#pragma unroll
    for (int j = 0; j < 8; ++j) ones[j] = (short)0x3F80;   // bf16 1.0

#pragma unroll
    for (int mt = 0; mt < 4; ++mt) {
        // scores s_p = a_p * b_{p/2}; cols of wave tile: [0,64)=a, [64,96)=b
#pragma unroll
        for (int nt = 0; nt < 4; ++nt) {
            const int src = (nt & 1) ? srcl1 : srcl0;
#pragma unroll
            for (int r = 0; r < 4; ++r) {
                float bsh = __shfl(acc[mt][4 + (nt >> 1)][r], src, 64);
                float e = __expf(acc[mt][nt][r] * bsh);
                Pw[(mt * 16 + quad * 4 + r) * 72 + nt * 16 + l16] = f2bf(e);
            }
        }
        // PV for this 16-row tile (wave-local)
        short8 a0 = *(const short8*)&Pw[(mt * 16 + l16) * 72 + quad * 8];
        short8 a1 = *(const short8*)&Pw[(mt * 16 + l16) * 72 + 32 + quad * 8];
        floatx4 sacc = {};
        sacc = __builtin_amdgcn_mfma_f32_16x16x32_bf16(a0, ones, sacc, 0, 0, 0);
        sacc = __builtin_amdgcn_mfma_f32_16x16x32_bf16(a1, ones, sacc, 0, 0, 0);
        floatx4 accO[4] = {};
#pragma unroll
        for (int nt2 = 0; nt2 < 4; ++nt2) {
            accO[nt2] = __builtin_amdgcn_mfma_f32_16x16x32_bf16(a0, bV[nt2][0], accO[nt2], 0, 0, 0);
            accO[nt2] = __builtin_amdgcn_mfma_f32_16x16x32_bf16(a1, bV[nt2][1], accO[nt2], 0, 0, 0);
        }
        float inv[4];
#pragma unroll
        for (int r = 0; r < 4; ++r) inv[r] = 1.0f / (32.0f * sacc[r]);
#pragma unroll
        for (int nt2 = 0; nt2 < 4; ++nt2)
#pragma unroll
            for (int rr = 0; rr < 4; ++rr) {
                const size_t row = (size_t)(m0 + wm + mt * 16 + quad * 4 + rr);
                Hb[row * DIMC + h * 64 + nt2 * 16 + l16] =
                    f2bf(accO[nt2][rr] * inv[rr]);
            }
    }
}

// ---------------------------------------------------------------------------
extern "C" void kernel_launch(void* const* d_in, const int* in_sizes, int n_in,
                              void* d_out, int out_size, void* d_ws, size_t ws_size,
                              hipStream_t stream)
{
    const float* x  = (const float*)d_in[0];
    const float* Wa = (const float*)d_in[1];
    const float* Wb = (const float*)d_in[2];
    const float* Wv = (const float*)d_in[3];
    const float* Wp = (const float*)d_in[4];
    const float* bp = (const float*)d_in[5];
    float* out = (float*)d_out;

    char* ws = (char*)d_ws;
    u16*   xb    = (u16*)ws;   ws += (size_t)MROWS * DIMC * 2;   // 12.6 MB
    u16*   Wtcat = (u16*)ws;   ws += (size_t)NCAT * DIMC * 2;    // 2.9 MB
    u16*   Wpt   = (u16*)ws;   ws += (size_t)DIMC * DIMC * 2;    // 1.2 MB
    u16*   xs    = (u16*)ws;   ws += (size_t)256 * DIMC * 2;     // 0.4 MB
    u16*   VsT   = (u16*)ws;   ws += (size_t)48 * 4096 * 2;      // 0.4 MB
    u16*   Hb    = (u16*)ws;                                     // 12.6 MB

    dim3 blk(256);

    prep_kernel<<<dim3(3832), blk, 0, stream>>>(x, Wa, Wb, Wv, Wp,
                                                xb, Wtcat, Wpt, xs);

    vs_kernel<<<dim3(48), blk, 0, stream>>>(xs, Wtcat + (size_t)NAB * DIMC, VsT);

    gemm1_attn_kernel<<<dim3(MROWS / 128, NAB / 192), blk, 0, stream>>>(
        xb, Wtcat, VsT, Hb);

    gemm_bf16_kernel<false><<<dim3(MROWS / 128, DIMC / 128), blk, 0, stream>>>(
        Hb, Wpt, bp, out, DIMC, DIMC);
}

// Round 4
// 153.569 us; speedup vs baseline: 1.1795x; 1.0428x over previous
//
#include <hip/hip_runtime.h>
#include <hip/hip_bf16.h>
#include <cstddef>

#define DIMC   768
#define HEADS  12
#define BATCH  4
#define SEQ    2048
#define MROWS  (BATCH * SEQ)      // 8192
#define NCAT   1920               // Wtcat rows: 1152 (head-major [Wa|Wb]) + 768 (Wv)
#define NAB    1152

typedef unsigned short u16;
typedef __attribute__((ext_vector_type(8))) short short8;   // 8 bf16 = 4 VGPRs
typedef __attribute__((ext_vector_type(4))) float floatx4;  // MFMA C/D

__device__ inline u16 f2bf(float f) {
    union { float f; unsigned u; } v; v.f = f;
    unsigned u = v.u + 0x7FFF + ((v.u >> 16) & 1);   // RNE
    return (u16)(u >> 16);
}
__device__ inline float bf2f(u16 h) {
    union { unsigned u; float f; } v; v.u = ((unsigned)h) << 16;
    return v.f;
}

// async 16B/lane global->LDS; lane i lands at lptr + i*16 (wave-uniform base)
__device__ inline void async_load16(const void* g, void* l) {
    __builtin_amdgcn_global_load_lds(
        (const __attribute__((address_space(1))) void*)g,
        (__attribute__((address_space(3))) void*)l, 16, 0, 0);
}

// ---------------------------------------------------------------------------
// Fused prep (unchanged):
//  [0,3072)      x fp32 -> xb bf16 (8 elem/thread)
//  [3072,3432)   Wtcat 64x64 tile-transpose from [Wa|Wb|Wv]
//                ab rows HEAD-MAJOR: head h rows [h*96,h*96+96) =
//                64 Wa cols (h*64..) then 32 Wb cols (h*32..)
//  [3432,3576)   Wpt from Wp
//  [3576,3832)   xs-pool: xs[p][c] = sum_{j<32} x[(p*32+j)*768 + c] (bf16)
// ---------------------------------------------------------------------------
__global__ __launch_bounds__(256)
void prep_kernel(const float* __restrict__ x,
                 const float* __restrict__ Wa, const float* __restrict__ Wb,
                 const float* __restrict__ Wv, const float* __restrict__ Wp,
                 u16* __restrict__ xb, u16* __restrict__ Wtcat,
                 u16* __restrict__ Wpt, u16* __restrict__ xs)
{
    const int tid = threadIdx.x;
    const int bidg = blockIdx.x;
    if (bidg < 3072) {
        int i = bidg * 256 + tid;
        const float4 f0 = ((const float4*)x)[(size_t)i * 2];
        const float4 f1 = ((const float4*)x)[(size_t)i * 2 + 1];
        u16 tmp[8] = { f2bf(f0.x), f2bf(f0.y), f2bf(f0.z), f2bf(f0.w),
                       f2bf(f1.x), f2bf(f1.y), f2bf(f1.z), f2bf(f1.w) };
        *(uint4*)&xb[(size_t)i * 8] = *(uint4*)tmp;
        return;
    }
    if (bidg >= 3576) {
        const int p = bidg - 3576;                 // [0,256)
#pragma unroll
        for (int k = 0; k < 3; ++k) {
            const int c = k * 256 + tid;
            const float* src = x + (size_t)p * 32 * DIMC + c;
            float s = 0.f;
#pragma unroll
            for (int j = 0; j < 32; ++j) s += src[(size_t)j * DIMC];
            xs[(size_t)p * DIMC + c] = f2bf(s);
        }
        return;
    }
    __shared__ u16 tile[64 * 72];
    int bid = bidg - 3072;
    const float* src; u16* dst; int n0, k0, ld, col0;
    bool remap = false;
    if (bid < 360) {
        int nt = bid / 12, kt = bid % 12;
        n0 = nt * 64; k0 = kt * 64; dst = Wtcat;
        if (n0 < 768)       { src = Wa; ld = 768; col0 = n0; remap = true; }
        else if (n0 < 1152) { src = Wb; ld = 384; col0 = n0 - 768; remap = true; }
        else                { src = Wv; ld = 768; col0 = n0 - 1152; }
    } else {
        int b2 = bid - 360;
        int nt = b2 / 12, kt = b2 % 12;
        n0 = nt * 64; k0 = kt * 64; dst = Wpt; src = Wp; ld = 768; col0 = n0;
    }
#pragma unroll
    for (int p = 0; p < 16; ++p) {
        int i = p * 256 + tid;
        int k = i >> 6, n = i & 63;
        tile[n * 72 + k] = f2bf(src[(size_t)(k0 + k) * ld + col0 + n]);
    }
    __syncthreads();
    int n = tid >> 2, kc = (tid & 3) * 16;
    int orow = n0 + n;
    int drow = orow;
    if (remap) {
        if (orow < 768) drow = (orow >> 6) * 96 + (orow & 63);              // Wa
        else { int c = orow - 768; drow = (c >> 5) * 96 + 64 + (c & 31); }  // Wb
    }
    uint4 o0 = *(uint4*)&tile[n * 72 + kc];
    uint4 o1 = *(uint4*)&tile[n * 72 + kc + 8];
    *(uint4*)&dst[(size_t)drow * DIMC + k0 + kc] = o0;
    *(uint4*)&dst[(size_t)drow * DIMC + k0 + kc + 8] = o1;
}

// ---------------------------------------------------------------------------
// bf16 MFMA GEMM — validated; used for gemm2 only.
// ---------------------------------------------------------------------------
template<bool WRITE_BF16>
__global__ __launch_bounds__(256)
void gemm_bf16_kernel(const u16* __restrict__ A, const u16* __restrict__ Bt,
                      const float* __restrict__ bias, void* __restrict__ Cout,
                      int K, int ldC)
{
    __shared__ u16 As[2][4096];
    __shared__ u16 Bs[2][4096];

    const int tid  = threadIdx.x;
    const int lane = tid & 63, wave = tid >> 6;
    const int quad = lane >> 4, l16 = lane & 15;
    const int wm = (wave & 1) * 64, wn = (wave >> 1) * 64;
    const int m0 = blockIdx.x * 128, n0 = blockIdx.y * 128;

    const int lrow = lane >> 2, lchunk = lane & 3;
    const u16* gA = A  + (size_t)(m0 + wave * 32 + lrow) * K + lchunk * 8;
    const u16* gB = Bt + (size_t)(n0 + wave * 32 + lrow) * K + lchunk * 8;
    const int NT = K / 32;   // 24

#define STAGE(buf, kt_) do {                                                  \
        const int _k0 = (kt_) * 32;                                           \
        async_load16(gA + _k0,          &As[buf][wave * 1024]);               \
        async_load16(gA + _k0 + 16 * K, &As[buf][wave * 1024 + 512]);         \
        async_load16(gB + _k0,          &Bs[buf][wave * 1024]);               \
        async_load16(gB + _k0 + 16 * K, &Bs[buf][wave * 1024 + 512]);         \
    } while (0)

#define COMPUTE(buf) do {                                                     \
        short8 af[4], bf[4];                                                  \
        _Pragma("unroll")                                                     \
        for (int t = 0; t < 4; ++t) {                                         \
            af[t] = *(short8*)&As[buf][(wm + t * 16 + l16) * 32 + quad * 8];  \
            bf[t] = *(short8*)&Bs[buf][(wn + t * 16 + l16) * 32 + quad * 8];  \
        }                                                                     \
        _Pragma("unroll")                                                     \
        for (int mt = 0; mt < 4; ++mt)                                        \
            _Pragma("unroll")                                                 \
            for (int nt = 0; nt < 4; ++nt)                                    \
                acc[mt][nt] = __builtin_amdgcn_mfma_f32_16x16x32_bf16(        \
                    af[mt], bf[nt], acc[mt][nt], 0, 0, 0);                    \
    } while (0)

    floatx4 acc[4][4] = {};
    STAGE(0, 0);
    STAGE(1, 1);
#pragma unroll 2
    for (int kt = 0; kt < NT; ++kt) {
        const int buf = kt & 1;
        __asm__ volatile("s_waitcnt vmcnt(4)" ::: "memory");
        __asm__ volatile("s_barrier" ::: "memory");
        COMPUTE(buf);
        __asm__ volatile("s_barrier" ::: "memory");
        STAGE(buf, (kt + 2) % NT);
    }
#undef STAGE
#undef COMPUTE

#pragma unroll
    for (int mt = 0; mt < 4; ++mt)
#pragma unroll
        for (int nt = 0; nt < 4; ++nt) {
            const int gc = n0 + wn + nt * 16 + l16;
            const float bv = bias ? bias[gc] : 0.f;
#pragma unroll
            for (int r = 0; r < 4; ++r) {
                const int gr = m0 + wm + mt * 16 + quad * 4 + r;
                const float v = acc[mt][nt][r] + bv;
                if (WRITE_BF16) ((u16*)Cout)[(size_t)gr * ldC + gc] = f2bf(v);
                else            ((float*)Cout)[(size_t)gr * ldC + gc] = v;
            }
        }
}

// ---------------------------------------------------------------------------
// Vs kernel — unchanged (validated). VsT[bh][d][t] bf16.
// ---------------------------------------------------------------------------
__global__ __launch_bounds__(256)
void vs_kernel(const u16* __restrict__ xs, const u16* __restrict__ Wvt,
               u16* __restrict__ VsT)
{
    const int tid = threadIdx.x;
    const int lane = tid & 63, wave = tid >> 6;
    const int quad = lane >> 4, l16 = lane & 15;
    const int bh = blockIdx.x;
    const int b = bh / HEADS, h = bh % HEADS;
    const int K = DIMC;

    const u16* gA = Wvt + (size_t)(h * 64 + wave * 16 + l16) * K + quad * 8;
    const u16* gB = xs  + (size_t)(b * 64 + l16) * K + quad * 8;

    floatx4 acc[4] = {};
    for (int it = 0; it < 24; ++it) {
        short8 af = *(const short8*)(gA + it * 32);
        short8 bf[4];
#pragma unroll
        for (int nt = 0; nt < 4; ++nt)
            bf[nt] = *(const short8*)(gB + (size_t)nt * 16 * K + it * 32);
#pragma unroll
        for (int nt = 0; nt < 4; ++nt)
            acc[nt] = __builtin_amdgcn_mfma_f32_16x16x32_bf16(
                af, bf[nt], acc[nt], 0, 0, 0);
    }
#pragma unroll
    for (int nt = 0; nt < 4; ++nt)
#pragma unroll
        for (int r = 0; r < 4; ++r) {
            const int d = wave * 16 + quad * 4 + r;
            const int t = nt * 16 + l16;
            VsT[(size_t)bh * 4096 + d * 64 + t] = f2bf(acc[nt][r]);
        }
}

// ---------------------------------------------------------------------------
// FUSED gemm1 + attention, RETILED 64x192 for occupancy.
// 4 waves; wave w owns rows (w&1)*32, head (w>>1): 32x96 sub-tile = full
// head -> wave-local softmax. acc[2][6] = 48 VGPR (was 96) -> 3 waves/SIMD.
// Grid 128x6 = 768 blocks = exactly 3 blocks/CU (perfect balance).
// Staging: 4 async loads/thread/K-step (1 A + 3 B), vmcnt(4) dbuf discipline
// identical to validated gemm. Tail: vmcnt+barrier before EVERY compute.
// ---------------------------------------------------------------------------
__global__ __launch_bounds__(256, 3)
void gemm1_attn_kernel(const u16* __restrict__ xb, const u16* __restrict__ Wab,
                       const u16* __restrict__ VsT, u16* __restrict__ Hb)
{
    __shared__ u16 smem[16384];   // 32 KB: A dbuf 2x2048, B dbuf 2x6144 (u16)

    const int tid  = threadIdx.x;
    const int lane = tid & 63, wave = tid >> 6;
    const int quad = lane >> 4, l16 = lane & 15;
    const int wm = (wave & 1) * 32;          // row half (32 rows)
    const int wn = (wave >> 1) * 96;         // col half = one head
    const int m0 = blockIdx.x * 64, n0 = blockIdx.y * 192;
    const int K = DIMC;
    const int NT = K / 32;                   // 24

    const int lrow = lane >> 2, lchunk = lane & 3;
    const u16* gA = xb  + (size_t)(m0 + wave * 16 + lrow) * K + lchunk * 8;
    const u16* gB = Wab + (size_t)(n0 + wave * 48 + lrow) * K + lchunk * 8;

    // As[buf] = smem + buf*2048 (64x32); Bs[buf] = smem + 4096 + buf*6144 (192x32)
#define STAGE(buf, kt_) do {                                                  \
        const int _k0 = (kt_) * 32;                                           \
        u16* _as = smem + (buf) * 2048 + wave * 512;                          \
        u16* _bs = smem + 4096 + (buf) * 6144 + wave * 1536;                  \
        async_load16(gA + _k0,          _as);                                 \
        async_load16(gB + _k0,          _bs);                                 \
        async_load16(gB + _k0 + 16 * K, _bs + 512);                          \
        async_load16(gB + _k0 + 32 * K, _bs + 1024);                         \
    } while (0)

#define COMPUTE(buf) do {                                                     \
        const u16* _as = smem + (buf) * 2048;                                 \
        const u16* _bs = smem + 4096 + (buf) * 6144;                          \
        short8 af[2], bfr[6];                                                 \
        _Pragma("unroll")                                                     \
        for (int t = 0; t < 2; ++t)                                           \
            af[t] = *(const short8*)&_as[(wm + t * 16 + l16) * 32 + quad * 8];\
        _Pragma("unroll")                                                     \
        for (int t = 0; t < 6; ++t)                                           \
            bfr[t] = *(const short8*)&_bs[(wn + t * 16 + l16) * 32 + quad * 8];\
        _Pragma("unroll")                                                     \
        for (int mt = 0; mt < 2; ++mt)                                        \
            _Pragma("unroll")                                                 \
            for (int ct = 0; ct < 6; ++ct)                                    \
                acc[mt][ct] = __builtin_amdgcn_mfma_f32_16x16x32_bf16(        \
                    af[mt], bfr[ct], acc[mt][ct], 0, 0, 0);                   \
    } while (0)

    floatx4 acc[2][6] = {};
    STAGE(0, 0);
    STAGE(1, 1);
#pragma unroll 2
    for (int kt = 0; kt < NT - 2; ++kt) {
        const int buf = kt & 1;
        __asm__ volatile("s_waitcnt vmcnt(4)" ::: "memory");
        __asm__ volatile("s_barrier" ::: "memory");
        COMPUTE(buf);
        __asm__ volatile("s_barrier" ::: "memory");
        STAGE(buf, kt + 2);
    }
    __asm__ volatile("s_waitcnt vmcnt(4)" ::: "memory");
    __asm__ volatile("s_barrier" ::: "memory");
    COMPUTE(0);                                  // kt = 22
    __asm__ volatile("s_waitcnt vmcnt(0)" ::: "memory");
    __asm__ volatile("s_barrier" ::: "memory");  // cross-wave staging complete
    COMPUTE(1);                                  // kt = 23
    __syncthreads();                             // staging LDS dead -> P overlay
#undef STAGE
#undef COMPUTE

    // ---------------- fused attention epilogue (wave-local) ----------------
    const int b = blockIdx.x >> 5;               // m0 / 2048
    const int h = blockIdx.y * 2 + (wave >> 1);
    const u16* vbase = VsT + ((size_t)b * HEADS + h) * 4096;

    short8 bV[4][2];
#pragma unroll
    for (int nt2 = 0; nt2 < 4; ++nt2)
#pragma unroll
        for (int kk = 0; kk < 2; ++kk)
            bV[nt2][kk] = *(const short8*)
                &vbase[(nt2 * 16 + l16) * 64 + kk * 32 + quad * 8];

    u16* Pw = smem + wave * 2304;                // 32 x 72 bf16, per wave
    const int srcl0 = quad * 16 + (l16 >> 1);    // b-col p>>1, frag-local
    const int srcl1 = srcl0 + 8;

    short8 ones;
#pragma unroll
    for (int j = 0; j < 8; ++j) ones[j] = (short)0x3F80;   // bf16 1.0

#pragma unroll
    for (int mt = 0; mt < 2; ++mt) {
        // scores s_p = a_p * b_{p/2}; cols of wave tile: [0,64)=a, [64,96)=b
#pragma unroll
        for (int nt = 0; nt < 4; ++nt) {
            const int src = (nt & 1) ? srcl1 : srcl0;
#pragma unroll
            for (int r = 0; r < 4; ++r) {
                float bsh = __shfl(acc[mt][4 + (nt >> 1)][r], src, 64);
                float e = __expf(acc[mt][nt][r] * bsh);
                Pw[(mt * 16 + quad * 4 + r) * 72 + nt * 16 + l16] = f2bf(e);
            }
        }
        // PV for this 16-row tile (wave-local)
        short8 a0 = *(const short8*)&Pw[(mt * 16 + l16) * 72 + quad * 8];
        short8 a1 = *(const short8*)&Pw[(mt * 16 + l16) * 72 + 32 + quad * 8];
        floatx4 sacc = {};
        sacc = __builtin_amdgcn_mfma_f32_16x16x32_bf16(a0, ones, sacc, 0, 0, 0);
        sacc = __builtin_amdgcn_mfma_f32_16x16x32_bf16(a1, ones, sacc, 0, 0, 0);
        floatx4 accO[4] = {};
#pragma unroll
        for (int nt2 = 0; nt2 < 4; ++nt2) {
            accO[nt2] = __builtin_amdgcn_mfma_f32_16x16x32_bf16(a0, bV[nt2][0], accO[nt2], 0, 0, 0);
            accO[nt2] = __builtin_amdgcn_mfma_f32_16x16x32_bf16(a1, bV[nt2][1], accO[nt2], 0, 0, 0);
        }
        float inv[4];
#pragma unroll
        for (int r = 0; r < 4; ++r) inv[r] = 1.0f / (32.0f * sacc[r]);
#pragma unroll
        for (int nt2 = 0; nt2 < 4; ++nt2)
#pragma unroll
            for (int rr = 0; rr < 4; ++rr) {
                const size_t row = (size_t)(m0 + wm + mt * 16 + quad * 4 + rr);
                Hb[row * DIMC + h * 64 + nt2 * 16 + l16] =
                    f2bf(accO[nt2][rr] * inv[rr]);
            }
    }
}

// ---------------------------------------------------------------------------
extern "C" void kernel_launch(void* const* d_in, const int* in_sizes, int n_in,
                              void* d_out, int out_size, void* d_ws, size_t ws_size,
                              hipStream_t stream)
{
    const float* x  = (const float*)d_in[0];
    const float* Wa = (const float*)d_in[1];
    const float* Wb = (const float*)d_in[2];
    const float* Wv = (const float*)d_in[3];
    const float* Wp = (const float*)d_in[4];
    const float* bp = (const float*)d_in[5];
    float* out = (float*)d_out;

    char* ws = (char*)d_ws;
    u16*   xb    = (u16*)ws;   ws += (size_t)MROWS * DIMC * 2;   // 12.6 MB
    u16*   Wtcat = (u16*)ws;   ws += (size_t)NCAT * DIMC * 2;    // 2.9 MB
    u16*   Wpt   = (u16*)ws;   ws += (size_t)DIMC * DIMC * 2;    // 1.2 MB
    u16*   xs    = (u16*)ws;   ws += (size_t)256 * DIMC * 2;     // 0.4 MB
    u16*   VsT   = (u16*)ws;   ws += (size_t)48 * 4096 * 2;      // 0.4 MB
    u16*   Hb    = (u16*)ws;                                     // 12.6 MB

    dim3 blk(256);

    prep_kernel<<<dim3(3832), blk, 0, stream>>>(x, Wa, Wb, Wv, Wp,
                                                xb, Wtcat, Wpt, xs);

    vs_kernel<<<dim3(48), blk, 0, stream>>>(xs, Wtcat + (size_t)NAB * DIMC, VsT);

    gemm1_attn_kernel<<<dim3(MROWS / 64, NAB / 192), blk, 0, stream>>>(
        xb, Wtcat, VsT, Hb);

    gemm_bf16_kernel<false><<<dim3(MROWS / 128, DIMC / 128), blk, 0, stream>>>(
        Hb, Wpt, bp, out, DIMC, DIMC);
}